// Round 2
// baseline (786.663 us; speedup 1.0000x reference)
//
#include <hip/hip_runtime.h>
#include <stdint.h>

// out[b,s,o] = sum_i x[b,s,i] * (W[o,i] + sum_r A[o,r]*B[r,i]) + bias[o]
// M = 16384, N = 4096, K = 4096. fp32 in/out, bf16 MFMA compute.
// GEMM: 256x256 tile, BK=64, 8 waves, 8-phase schedule (T1+T2+T3+T4+T5).

#define MDIM 16384
#define NDIM 4096
#define KDIM 4096
#define RANK 16
#define NT   (KDIM / 64)   // 64 K-tiles

typedef __bf16  bf16x8 __attribute__((ext_vector_type(8)));
typedef float   f32x4  __attribute__((ext_vector_type(4)));
typedef unsigned short u16x8 __attribute__((ext_vector_type(8)));

__device__ __forceinline__ unsigned short f2bf(float f) {
  union { float f; uint32_t u; } v; v.f = f;
  uint32_t r = v.u + 0x7FFFu + ((v.u >> 16) & 1u);
  return (unsigned short)(r >> 16);
}

__device__ __forceinline__ void gl16(const void* g, void* l) {
  __builtin_amdgcn_global_load_lds(
      (__attribute__((address_space(1))) void*)(g),
      (__attribute__((address_space(3))) void*)(l),
      16, 0, 0);
}

// Wp[o][i] = bf16(W[o][i] + sum_r A[o][r]*B[r][i])
__global__ void prep_w(const float* __restrict__ W, const float* __restrict__ A,
                       const float* __restrict__ Bm, unsigned short* __restrict__ Wp) {
  const int i = blockIdx.x * 256 + threadIdx.x;
  const int o = blockIdx.y;
  float acc = W[(size_t)o * NDIM + i];
#pragma unroll
  for (int r = 0; r < RANK; ++r)
    acc += A[o * RANK + r] * Bm[(size_t)r * NDIM + i];
  Wp[(size_t)o * NDIM + i] = f2bf(acc);
}

// x fp32 -> bf16, 8 elems/thread
__global__ void cast_x(const float* __restrict__ x, unsigned short* __restrict__ xb) {
  const size_t i = ((size_t)blockIdx.x * 256 + threadIdx.x) * 8;
  float4 a = *(const float4*)(x + i);
  float4 b = *(const float4*)(x + i + 4);
  u16x8 o;
  o[0] = f2bf(a.x); o[1] = f2bf(a.y); o[2] = f2bf(a.z); o[3] = f2bf(a.w);
  o[4] = f2bf(b.x); o[5] = f2bf(b.y); o[6] = f2bf(b.z); o[7] = f2bf(b.w);
  *(u16x8*)(xb + i) = o;
}

#define BARRIER  __builtin_amdgcn_s_barrier()
#define WAITLGKM asm volatile("s_waitcnt lgkmcnt(0)" ::: "memory")
#define WAITVM2  asm volatile("s_waitcnt vmcnt(2)" ::: "memory")
#define WAITVM0  asm volatile("s_waitcnt vmcnt(0)" ::: "memory")
#define SCHEDB   __builtin_amdgcn_sched_barrier(0)

// Stage one half-tile (128 rows of A or B K-tile) = 2 x global_load_lds(16B).
// h4: bit1 = tensor (0=A,1=B), bit0 = row-half. Source is inverse-swizzled
// (ske), LDS dest linear in t -> LDS ends up swizzle-laid-out (rule #21).
#define STAGE(buf, h4, kt) do {                                                   \
    const int kc_ = ((kt) < NT ? (kt) : NT - 1);                                  \
    const unsigned short* g_ = (((h4) & 2) ? bgb : agb)                           \
        + (size_t)(((h4) & 1) * 128) * KDIM + kc_ * 64;                           \
    unsigned short* d_ = (((h4) & 2) ? &sB[(buf)][0] : &sA[(buf)][0])             \
        + ((h4) & 1) * 8192 + t * 8;                                              \
    gl16(g_, d_);                                                                 \
    gl16(g_ + (size_t)64 * KDIM, d_ + 4096);                                      \
  } while (0)

#define LDA(buf, mh) do {                                                         \
    _Pragma("unroll") for (int mi = 0; mi < 4; ++mi)                              \
    _Pragma("unroll") for (int kk = 0; kk < 2; ++kk)                              \
      a[mi][kk] = *(const bf16x8*)(saw + (buf)*16384 + ((mh)*64 + mi*16)*64 + kk*32); \
  } while (0)

#define LDB(buf, nh, bb) do {                                                     \
    _Pragma("unroll") for (int ni = 0; ni < 2; ++ni)                              \
    _Pragma("unroll") for (int kk = 0; kk < 2; ++kk)                              \
      bb[ni][kk] = *(const bf16x8*)(sbw + (buf)*16384 + ((nh)*32 + ni*16)*64 + kk*32); \
  } while (0)

#define MM(mh, nh, bb) do {                                                       \
    __builtin_amdgcn_s_setprio(1);                                                \
    _Pragma("unroll") for (int mi = 0; mi < 4; ++mi)                              \
    _Pragma("unroll") for (int ni = 0; ni < 2; ++ni)                              \
    _Pragma("unroll") for (int kk = 0; kk < 2; ++kk)                              \
      acc[(mh)*4+mi][(nh)*2+ni] = __builtin_amdgcn_mfma_f32_16x16x32_bf16(        \
          a[mi][kk], bb[ni][kk], acc[(mh)*4+mi][(nh)*2+ni], 0, 0, 0);             \
    __builtin_amdgcn_s_setprio(0);                                                \
  } while (0)

__global__ __launch_bounds__(512, 2) void gemm256(
    const unsigned short* __restrict__ Xb,
    const unsigned short* __restrict__ Wp,
    const float* __restrict__ bias,
    float* __restrict__ out) {
  __shared__ __align__(16) unsigned short sA[2][256 * 64];  // 64 KiB
  __shared__ __align__(16) unsigned short sB[2][256 * 64];  // 64 KiB

  const int t  = threadIdx.x;
  const int l  = t & 63;
  const int w  = t >> 6;   // 0..7
  const int wm = w >> 2;   // 0..1  (m half: 128 rows)
  const int wn = w & 3;    // 0..3  (n quarter: 64 cols)

  // XCD-aware bijective swizzle (1024 blocks % 8 == 0), column-major tiles
  const int bid = blockIdx.x;
  const int swz = (bid & 7) * (1024 / 8) + (bid >> 3);
  const int bm  = (swz & 63) * 256;   // 64 m-tiles (fastest -> share B panel)
  const int bn  = (swz >> 6) * 256;   // 16 n-tiles

  // ---- staging addresses: thread t covers row sr, 16B at swizzled k ----
  const int sr  = t >> 3;  // 0..63
  const int ske = ((((t & 7) * 16) ^ (((sr >> 2) & 1) << 5) ^ (((sr >> 3) & 1) << 4)) >> 1);
  const unsigned short* agb = Xb + (size_t)(bm + sr) * KDIM + ske;
  const unsigned short* bgb = Wp + (size_t)(bn + sr) * KDIM + ske;

  // ---- ds_read addresses: lane l reads row (base + l&15), 16B at swizzled k
  const int lr  = l & 15;
  const int kph = ((l >> 4) * 8) ^ (((lr >> 2) & 1) << 4) ^ (((lr >> 3) & 1) << 3);
  const unsigned short* saw = &sA[0][0] + (wm * 128 + lr) * 64 + kph;
  const unsigned short* sbw = &sB[0][0] + (wn * 64 + lr) * 64 + kph;

  bf16x8 a[4][2], b0[2][2], b1[2][2];
  f32x4 acc[8][4];
#pragma unroll
  for (int i = 0; i < 8; ++i)
#pragma unroll
    for (int j = 0; j < 4; ++j)
      acc[i][j] = f32x4{0.f, 0.f, 0.f, 0.f};

  // ---- prologue: tile0 fully + tile1 h0; wait tile0 landed (2 in flight)
  STAGE(0, 0, 0); STAGE(0, 1, 0); STAGE(0, 2, 0); STAGE(0, 3, 0);
  STAGE(1, 0, 1);
  WAITVM2;
  BARRIER;

  // ---- main loop: 2 K-tiles per iteration, 8 phases ----
  for (int it = 0; it < NT / 2; ++it) {
    const int E = it * 2;
    // ph1 (buf0): A half0 + B frags 0,1
    LDA(0, 0); LDB(0, 0, b0);
    STAGE(1, 1, E + 1);
    BARRIER; WAITLGKM; SCHEDB;
    MM(0, 0, b0);
    BARRIER;
    // ph2: B frags 2,3
    LDB(0, 1, b1);
    STAGE(1, 2, E + 1);
    BARRIER; WAITLGKM; SCHEDB;
    MM(0, 1, b1);
    BARRIER;
    // ph3: A half1
    LDA(0, 1);
    STAGE(1, 3, E + 1);
    BARRIER; WAITLGKM; SCHEDB;
    MM(1, 1, b1);
    BARRIER;
    // ph4: no ds_read; ensure buf1 (tile E+1) landed before ph5
    STAGE(0, 0, E + 2);
    BARRIER;
    MM(1, 0, b0);
    WAITVM2;
    BARRIER;
    // ph5 (buf1)
    LDA(1, 0); LDB(1, 0, b0);
    STAGE(0, 1, E + 2);
    BARRIER; WAITLGKM; SCHEDB;
    MM(0, 0, b0);
    BARRIER;
    // ph6
    LDB(1, 1, b1);
    STAGE(0, 2, E + 2);
    BARRIER; WAITLGKM; SCHEDB;
    MM(0, 1, b1);
    BARRIER;
    // ph7
    LDA(1, 1);
    STAGE(0, 3, E + 2);
    BARRIER; WAITLGKM; SCHEDB;
    MM(1, 1, b1);
    BARRIER;
    // ph8: ensure buf0 (tile E+2) landed before next-iter ph1
    STAGE(1, 0, E + 3);
    BARRIER;
    MM(1, 0, b0);
    WAITVM2;
    BARRIER;
  }

  WAITVM0;  // drain stray prefetches before exit

  // ---- epilogue: C/D layout col=lane&15, row=(lane>>4)*4+reg ----
#pragma unroll
  for (int mf = 0; mf < 8; ++mf) {
#pragma unroll
    for (int nf = 0; nf < 4; ++nf) {
      const int row = bm + wm * 128 + mf * 16 + (l >> 4) * 4;
      const int col = bn + wn * 64 + nf * 16 + lr;
      const float bv = bias[col];
#pragma unroll
      for (int r = 0; r < 4; ++r)
        out[(size_t)(row + r) * NDIM + col] = acc[mf][nf][r] + bv;
    }
  }
}

extern "C" void kernel_launch(void* const* d_in, const int* in_sizes, int n_in,
                              void* d_out, int out_size, void* d_ws, size_t ws_size,
                              hipStream_t stream) {
  const float* x    = (const float*)d_in[0];
  const float* W    = (const float*)d_in[1];
  const float* bias = (const float*)d_in[2];
  const float* A    = (const float*)d_in[3];
  const float* B    = (const float*)d_in[4];
  float* out        = (float*)d_out;

  unsigned short* Wp = (unsigned short*)d_ws;                       // 32 MiB
  unsigned short* Xb = (unsigned short*)d_ws + (size_t)NDIM * KDIM; // 128 MiB

  prep_w<<<dim3(NDIM / 256, NDIM), 256, 0, stream>>>(W, A, B, Wp);
  cast_x<<<dim3((size_t)MDIM * KDIM / (256 * 8)), 256, 0, stream>>>(x, Xb);
  gemm256<<<dim3((MDIM / 256) * (NDIM / 256)), 512, 0, stream>>>(Xb, Wp, bias, out);
}

// Round 3
// 629.638 us; speedup vs baseline: 1.2494x; 1.2494x over previous
//
#include <hip/hip_runtime.h>
#include <stdint.h>

// out[b,s,o] = sum_i x[b,s,i] * (W[o,i] + sum_r A[o,r]*B[r,i]) + bias[o]
// M = 16384, N = 4096, K = 4096. fp32 in/out, bf16 MFMA compute.
// GEMM: 256x256 tile, BK=64, 8 waves, 8-phase schedule (T1+T2+T3+T4+T5).
// R3 fixes: full (row&7)<<4 XOR swizzle folded per-kk; n-fastest XCD mapping.

#define MDIM 16384
#define NDIM 4096
#define KDIM 4096
#define RANK 16
#define NT   (KDIM / 64)   // 64 K-tiles

typedef __bf16  bf16x8 __attribute__((ext_vector_type(8)));
typedef float   f32x4  __attribute__((ext_vector_type(4)));
typedef unsigned short u16x8 __attribute__((ext_vector_type(8)));

__device__ __forceinline__ unsigned short f2bf(float f) {
  union { float f; uint32_t u; } v; v.f = f;
  uint32_t r = v.u + 0x7FFFu + ((v.u >> 16) & 1u);
  return (unsigned short)(r >> 16);
}

__device__ __forceinline__ void gl16(const void* g, void* l) {
  __builtin_amdgcn_global_load_lds(
      (__attribute__((address_space(1))) void*)(g),
      (__attribute__((address_space(3))) void*)(l),
      16, 0, 0);
}

// Wp[o][i] = bf16(W[o][i] + sum_r A[o][r]*B[r][i])
__global__ void prep_w(const float* __restrict__ W, const float* __restrict__ A,
                       const float* __restrict__ Bm, unsigned short* __restrict__ Wp) {
  const int i = blockIdx.x * 256 + threadIdx.x;
  const int o = blockIdx.y;
  float acc = W[(size_t)o * NDIM + i];
#pragma unroll
  for (int r = 0; r < RANK; ++r)
    acc += A[o * RANK + r] * Bm[(size_t)r * NDIM + i];
  Wp[(size_t)o * NDIM + i] = f2bf(acc);
}

// x fp32 -> bf16, 8 elems/thread
__global__ void cast_x(const float* __restrict__ x, unsigned short* __restrict__ xb) {
  const size_t i = ((size_t)blockIdx.x * 256 + threadIdx.x) * 8;
  float4 a = *(const float4*)(x + i);
  float4 b = *(const float4*)(x + i + 4);
  u16x8 o;
  o[0] = f2bf(a.x); o[1] = f2bf(a.y); o[2] = f2bf(a.z); o[3] = f2bf(a.w);
  o[4] = f2bf(b.x); o[5] = f2bf(b.y); o[6] = f2bf(b.z); o[7] = f2bf(b.w);
  *(u16x8*)(xb + i) = o;
}

#define BARRIER  __builtin_amdgcn_s_barrier()
#define WAITLGKM asm volatile("s_waitcnt lgkmcnt(0)" ::: "memory")
#define WAITVM2  asm volatile("s_waitcnt vmcnt(2)" ::: "memory")
#define WAITVM0  asm volatile("s_waitcnt vmcnt(0)" ::: "memory")
#define SCHEDB   __builtin_amdgcn_sched_barrier(0)

// Stage one half-tile (128 rows of A or B K-tile) = 2 x global_load_lds(16B).
// h4: bit1 = tensor (0=A,1=B), bit0 = row-half. Source is inverse-swizzled
// (ske), LDS dest linear in t -> LDS ends up swizzle-laid-out (rule #21).
#define STAGE(buf, h4, kt) do {                                                   \
    const int kc_ = ((kt) < NT ? (kt) : NT - 1);                                  \
    const unsigned short* g_ = (((h4) & 2) ? bgb : agb)                           \
        + (size_t)(((h4) & 1) * 128) * KDIM + kc_ * 64;                           \
    unsigned short* d_ = (((h4) & 2) ? &sB[(buf)][0] : &sA[(buf)][0])             \
        + ((h4) & 1) * 8192 + t * 8;                                              \
    gl16(g_, d_);                                                                 \
    gl16(g_ + (size_t)64 * KDIM, d_ + 4096);                                      \
  } while (0)

// ds_read fragments. Element offset within a row: (kk*32 + koff) ^ xorE,
// where xorE = (row&7)<<3 elements ((row&7)<<4 bytes) — kk folded into the
// XOR so row-bit-2 -> byte-bit-6 is carry-safe.
#define LDA(buf, mh) do {                                                         \
    _Pragma("unroll") for (int mi = 0; mi < 4; ++mi)                              \
    _Pragma("unroll") for (int kk = 0; kk < 2; ++kk)                              \
      a[mi][kk] = *(const bf16x8*)(saw + (buf)*16384 + ((mh)*64 + mi*16)*64       \
                                   + ((kk*32 + koff) ^ xorE));                    \
  } while (0)

#define LDB(buf, nh, bb) do {                                                     \
    _Pragma("unroll") for (int ni = 0; ni < 2; ++ni)                              \
    _Pragma("unroll") for (int kk = 0; kk < 2; ++kk)                              \
      bb[ni][kk] = *(const bf16x8*)(sbw + (buf)*16384 + ((nh)*32 + ni*16)*64      \
                                    + ((kk*32 + koff) ^ xorE));                   \
  } while (0)

#define MM(mh, nh, bb) do {                                                       \
    __builtin_amdgcn_s_setprio(1);                                                \
    _Pragma("unroll") for (int mi = 0; mi < 4; ++mi)                              \
    _Pragma("unroll") for (int ni = 0; ni < 2; ++ni)                              \
    _Pragma("unroll") for (int kk = 0; kk < 2; ++kk)                              \
      acc[(mh)*4+mi][(nh)*2+ni] = __builtin_amdgcn_mfma_f32_16x16x32_bf16(        \
          a[mi][kk], bb[ni][kk], acc[(mh)*4+mi][(nh)*2+ni], 0, 0, 0);             \
    __builtin_amdgcn_s_setprio(0);                                                \
  } while (0)

__global__ __launch_bounds__(512, 2) void gemm256(
    const unsigned short* __restrict__ Xb,
    const unsigned short* __restrict__ Wp,
    const float* __restrict__ bias,
    float* __restrict__ out) {
  __shared__ __align__(16) unsigned short sA[2][256 * 64];  // 64 KiB
  __shared__ __align__(16) unsigned short sB[2][256 * 64];  // 64 KiB

  const int t  = threadIdx.x;
  const int l  = t & 63;
  const int w  = t >> 6;   // 0..7
  const int wm = w >> 2;   // 0..1  (m half: 128 rows)
  const int wn = w & 3;    // 0..3  (n quarter: 64 cols)

  // XCD-aware bijective swizzle (1024 blocks, 1024%8==0); n-fastest tiles:
  // each XCD owns an 8-bm-row band and sweeps all 16 bn per bm row.
  const int bid = blockIdx.x;
  const int swz = (bid & 7) * (1024 / 8) + (bid >> 3);
  const int bm  = (swz >> 4) * 256;   // 64 m-tiles
  const int bn  = (swz & 15) * 256;   // 16 n-tiles

  // ---- staging addresses: thread t covers row sr, 16B at inverse-swizzled k
  const int sr  = t >> 3;  // 0..63
  const int ske = (((t & 7) * 16) ^ ((sr & 7) << 4)) >> 1;  // bytes -> elements
  const unsigned short* agb = Xb + (size_t)(bm + sr) * KDIM + ske;
  const unsigned short* bgb = Wp + (size_t)(bn + sr) * KDIM + ske;

  // ---- ds_read addressing components ----
  const int lr   = l & 15;
  const int koff = (l >> 4) * 8;      // elements
  const int xorE = (lr & 7) << 3;     // elements ((row&7)<<4 bytes)
  const unsigned short* saw = &sA[0][0] + (wm * 128 + lr) * 64;
  const unsigned short* sbw = &sB[0][0] + (wn * 64 + lr) * 64;

  bf16x8 a[4][2], b0[2][2], b1[2][2];
  f32x4 acc[8][4];
#pragma unroll
  for (int i = 0; i < 8; ++i)
#pragma unroll
    for (int j = 0; j < 4; ++j)
      acc[i][j] = f32x4{0.f, 0.f, 0.f, 0.f};

  // ---- prologue: tile0 fully + tile1 h0; wait tile0 landed (2 in flight)
  STAGE(0, 0, 0); STAGE(0, 1, 0); STAGE(0, 2, 0); STAGE(0, 3, 0);
  STAGE(1, 0, 1);
  WAITVM2;
  BARRIER;

  // ---- main loop: 2 K-tiles per iteration, 8 phases ----
  for (int it = 0; it < NT / 2; ++it) {
    const int E = it * 2;
    // ph1 (buf0): A half0 + B frags 0,1
    LDA(0, 0); LDB(0, 0, b0);
    STAGE(1, 1, E + 1);
    BARRIER; WAITLGKM; SCHEDB;
    MM(0, 0, b0);
    BARRIER;
    // ph2: B frags 2,3
    LDB(0, 1, b1);
    STAGE(1, 2, E + 1);
    BARRIER; WAITLGKM; SCHEDB;
    MM(0, 1, b1);
    BARRIER;
    // ph3: A half1
    LDA(0, 1);
    STAGE(1, 3, E + 1);
    BARRIER; WAITLGKM; SCHEDB;
    MM(1, 1, b1);
    BARRIER;
    // ph4: no ds_read; ensure buf1 (tile E+1) landed before ph5
    STAGE(0, 0, E + 2);
    BARRIER;
    MM(1, 0, b0);
    WAITVM2;
    BARRIER;
    // ph5 (buf1)
    LDA(1, 0); LDB(1, 0, b0);
    STAGE(0, 1, E + 2);
    BARRIER; WAITLGKM; SCHEDB;
    MM(0, 0, b0);
    BARRIER;
    // ph6
    LDB(1, 1, b1);
    STAGE(0, 2, E + 2);
    BARRIER; WAITLGKM; SCHEDB;
    MM(0, 1, b1);
    BARRIER;
    // ph7
    LDA(1, 1);
    STAGE(0, 3, E + 2);
    BARRIER; WAITLGKM; SCHEDB;
    MM(1, 1, b1);
    BARRIER;
    // ph8: ensure buf0 (tile E+2) landed before next-iter ph1
    STAGE(1, 0, E + 3);
    BARRIER;
    MM(1, 0, b0);
    WAITVM2;
    BARRIER;
  }

  WAITVM0;  // drain stray prefetches before exit

  // ---- epilogue: C/D layout col=lane&15, row=(lane>>4)*4+reg ----
#pragma unroll
  for (int mf = 0; mf < 8; ++mf) {
#pragma unroll
    for (int nf = 0; nf < 4; ++nf) {
      const int row = bm + wm * 128 + mf * 16 + (l >> 4) * 4;
      const int col = bn + wn * 64 + nf * 16 + lr;
      const float bv = bias[col];
#pragma unroll
      for (int r = 0; r < 4; ++r)
        out[(size_t)(row + r) * NDIM + col] = acc[mf][nf][r] + bv;
    }
  }
}

extern "C" void kernel_launch(void* const* d_in, const int* in_sizes, int n_in,
                              void* d_out, int out_size, void* d_ws, size_t ws_size,
                              hipStream_t stream) {
  const float* x    = (const float*)d_in[0];
  const float* W    = (const float*)d_in[1];
  const float* bias = (const float*)d_in[2];
  const float* A    = (const float*)d_in[3];
  const float* B    = (const float*)d_in[4];
  float* out        = (float*)d_out;

  unsigned short* Wp = (unsigned short*)d_ws;                       // 32 MiB
  unsigned short* Xb = (unsigned short*)d_ws + (size_t)NDIM * KDIM; // 128 MiB

  prep_w<<<dim3(NDIM / 256, NDIM), 256, 0, stream>>>(W, A, B, Wp);
  cast_x<<<dim3((size_t)MDIM * KDIM / (256 * 8)), 256, 0, stream>>>(x, Xb);
  gemm256<<<dim3((MDIM / 256) * (NDIM / 256)), 512, 0, stream>>>(Xb, Wp, bias, out);
}